// Round 1
// baseline (216.010 us; speedup 1.0000x reference)
//
#include <hip/hip_runtime.h>

// Problem constants
#define NPTS 100000
#define NCH 32      // n
#define KNB 32      // K
#define MCL 16      // M

constexpr int IB1  = 128;   // i-blocks in encoder partial kernel
constexpr int SBLK = 250;   // blocks in S-partial kernel
constexpr int STILE = 64;   // points per LDS tile in S kernel

// Workspace layout (bytes)
constexpr size_t OFF_ENC_PART = 0;                          // 32*128 doubles = 32768
constexpr size_t OFF_ENC      = 32768;                      // 32 doubles     = 256
constexpr size_t OFF_INVW2    = OFF_ENC + 256;              // 512 floats     = 2048
constexpr size_t OFF_INVS     = OFF_INVW2 + 2048;           // 1024 floats    = 4096
constexpr size_t OFF_SPART    = OFF_INVS + 4096;            // 250*1024 dbl   = 2048000
constexpr size_t OFF_GT       = OFF_SPART + 2048000;        // N*32 floats    = 12800000
// total ~14.9 MB

// ---------------------------------------------------------------------------
// Kernel 1: encoder matvec partials. encoded[j] = sum_i enc_w[j,i]*x[i]
// grid = 512 blocks: 4 j-groups x 128 i-blocks. f64 accumulation (threshold
// is 8*eps vs an f64 numpy reference).
__global__ __launch_bounds__(256) void k_enc_partial(
    const float* __restrict__ x, const float* __restrict__ enc_w,
    double* __restrict__ part) {
  int jg = blockIdx.x & 3;
  int ib = blockIdx.x >> 2;
  int j0 = jg * 8;
  int tid = threadIdx.x;
  double acc[8];
#pragma unroll
  for (int jj = 0; jj < 8; ++jj) acc[jj] = 0.0;
  for (int i = ib * 256 + tid; i < NPTS; i += IB1 * 256) {
    float xv = x[i];
#pragma unroll
    for (int jj = 0; jj < 8; ++jj)
      acc[jj] += (double)enc_w[(size_t)(j0 + jj) * NPTS + i] * (double)xv;
  }
#pragma unroll
  for (int jj = 0; jj < 8; ++jj) {
    double v = acc[jj];
#pragma unroll
    for (int off = 32; off >= 1; off >>= 1) v += __shfl_down(v, off);
    acc[jj] = v;
  }
  __shared__ double sw[4][8];
  int lane = tid & 63, w = tid >> 6;
  if (lane == 0)
    for (int jj = 0; jj < 8; ++jj) sw[w][jj] = acc[jj];
  __syncthreads();
  if (tid < 8) {
    double s = sw[0][tid] + sw[1][tid] + sw[2][tid] + sw[3][tid];
    part[(size_t)(j0 + tid) * IB1 + ib] = s;
  }
}

// ---------------------------------------------------------------------------
// Kernel 2: reduce encoder partials; bandwidths = bw_w@encoded + bw_b;
// invw2[m*32+j] = 1/w^2  (MU=1). One block, 512 threads (one per bw row).
__global__ __launch_bounds__(512) void k_head(
    const double* __restrict__ part, const float* __restrict__ enc_b,
    const float* __restrict__ bw_w, const float* __restrict__ bw_b,
    double* __restrict__ enc_out, float* __restrict__ invw2) {
  __shared__ double es[32];
  int tid = threadIdx.x;
  if (tid < 32) {
    double s = 0.0;
    for (int ib = 0; ib < IB1; ++ib) s += part[(size_t)tid * IB1 + ib];
    s += (double)enc_b[tid];
    enc_out[tid] = s;
    es[tid] = s;
  }
  __syncthreads();
  int r = tid;  // bw row = j*16 + m
  double wd = 0.0;
  for (int c = 0; c < 32; ++c) wd += (double)bw_w[r * 32 + c] * es[c];
  wd += (double)bw_b[r];
  int j = r >> 4, m = r & 15;
  invw2[m * 32 + j] = (float)(1.0 / (wd * wd));
}

// ---------------------------------------------------------------------------
// Kernel 3: gT[i*32+j] = (float)enc[j] * decoder[j*N+i]  (scaled transpose so
// the main kernel's neighbor gather is one contiguous 128B column read).
__global__ __launch_bounds__(256) void k_gt(
    const float* __restrict__ decoder, const double* __restrict__ enc,
    float* __restrict__ gT) {
  __shared__ float tile[32][33];
  __shared__ float ef[32];
  int tx = threadIdx.x & 31, ty = threadIdx.x >> 5;  // ty: 0..7
  if (threadIdx.x < 32) ef[threadIdx.x] = (float)enc[threadIdx.x];
  int i0 = blockIdx.x * 32;
  for (int jj = ty; jj < 32; jj += 8)
    tile[tx][jj] = decoder[(size_t)jj * NPTS + i0 + tx];
  __syncthreads();
  for (int ii = ty; ii < 32; ii += 8)
    gT[(size_t)(i0 + ii) * 32 + tx] = tile[ii][tx] * ef[tx];
}

// ---------------------------------------------------------------------------
// Kernel 4: S[j,k] partials. Thread (j,k) = (tid>>5, tid&31); LDS tiles of
// 64 points of d^2 and invw2[.,lab[i]]. f32 per-tile sum, f64 across tiles.
__global__ __launch_bounds__(1024) void k_spart(
    const float* __restrict__ nd, const int* __restrict__ labels,
    const float* __restrict__ invw2, double* __restrict__ spart) {
  __shared__ float iw[512];
  __shared__ float d2t[STILE * 32];
  __shared__ float ic[STILE * 32];
  int tid = threadIdx.x;
  if (tid < 512) iw[tid] = invw2[tid];
  int j = tid >> 5, k = tid & 31;
  double acc = 0.0;
  const int ntiles = (NPTS + STILE - 1) / STILE;  // 1563
  for (int tile = blockIdx.x; tile < ntiles; tile += SBLK) {
    int i0 = tile * STILE;
    __syncthreads();  // previous tile's readers done (also covers iw staging)
#pragma unroll
    for (int q = tid; q < STILE * 32; q += 1024) {
      int ii = q >> 5;
      int gi = i0 + ii;
      float v = (gi < NPTS) ? nd[(size_t)i0 * 32 + q] : 1.0e18f;
      d2t[q] = v * v;  // 1e36 for invalid -> relu term = 0
      int lab = (gi < NPTS) ? labels[gi] : 0;
      ic[q] = iw[lab * 32 + (q & 31)];
    }
    __syncthreads();
    float ts = 0.0f;
#pragma unroll 8
    for (int ii = 0; ii < STILE; ++ii)
      ts += fmaxf(fmaf(-d2t[ii * 32 + k], ic[ii * 32 + j], 1.0f), 0.0f);
    acc += (double)ts;
  }
  spart[(size_t)blockIdx.x * 1024 + tid] = acc;
}

// ---------------------------------------------------------------------------
// Kernel 5: reduce S partials -> invS[k*32+j] (f32). 4 blocks x 256.
__global__ __launch_bounds__(256) void k_sreduce(
    const double* __restrict__ spart, float* __restrict__ invS) {
  int t = blockIdx.x * 256 + threadIdx.x;  // 0..1023 = j*32+k
  double s = 0.0;
  for (int b = 0; b < SBLK; ++b) s += spart[(size_t)b * 1024 + t];
  int j = t >> 5, k = t & 31;
  invS[k * 32 + j] = (float)(1.0 / s);
}

// ---------------------------------------------------------------------------
// Kernel 6: main. One wave per point. lane = (h = k-half, j). nid/dist loaded
// once per point and broadcast per-k via __shfl. Gather gT column (128B per
// half-wave). f64 lane accumulation + full-wave shuffle reduce.
__global__ __launch_bounds__(256) void k_main(
    const float* __restrict__ nd, const int* __restrict__ nid,
    const int* __restrict__ labels, const float* __restrict__ gT,
    const float* __restrict__ invw2, const float* __restrict__ invS,
    float* __restrict__ out, int nwaves) {
  __shared__ float iw[512];
  __shared__ float is[1024];
  int tid = threadIdx.x;
  for (int q = tid; q < 512; q += 256) iw[q] = invw2[q];
  for (int q = tid; q < 1024; q += 256) is[q] = invS[q];
  __syncthreads();
  int lane = tid & 63;
  int w = tid >> 6;
  int j = lane & 31, h = lane >> 5;
  int wid = blockIdx.x * 4 + w;
  for (int i = wid; i < NPTS; i += nwaves) {
    int lab = labels[i];
    float iwv = iw[lab * 32 + j];
    int base = i * 32;
    int myid = nid[base + j];
    float myd = nd[base + j];
    double acc = 0.0;
#pragma unroll
    for (int kk = 0; kk < 16; ++kk) {
      int k = kk + (h << 4);
      int id = __shfl(myid, k);
      float dv = __shfl(myd, k);
      float t = fmaf(-dv * dv, iwv, 1.0f);
      t = fmaxf(t, 0.0f);
      float val = gT[(size_t)id * 32 + j] * (t * is[(k << 5) + j]);
      acc += (double)val;
    }
#pragma unroll
    for (int off = 32; off >= 1; off >>= 1) acc += __shfl_down(acc, off);
    if (lane == 0) out[i] = (float)acc;
  }
}

// ---------------------------------------------------------------------------
extern "C" void kernel_launch(void* const* d_in, const int* in_sizes, int n_in,
                              void* d_out, int out_size, void* d_ws,
                              size_t ws_size, hipStream_t stream) {
  const float* x       = (const float*)d_in[0];
  const float* enc_w   = (const float*)d_in[1];
  const float* enc_b   = (const float*)d_in[2];
  const float* decoder = (const float*)d_in[3];
  const float* bw_w    = (const float*)d_in[4];
  const float* bw_b    = (const float*)d_in[5];
  const float* nd      = (const float*)d_in[6];
  const int*   nid     = (const int*)d_in[7];
  const int*   labels  = (const int*)d_in[8];
  float* out = (float*)d_out;

  char* ws = (char*)d_ws;
  double* part  = (double*)(ws + OFF_ENC_PART);
  double* enc_d = (double*)(ws + OFF_ENC);
  float*  invw2 = (float*)(ws + OFF_INVW2);
  float*  invS  = (float*)(ws + OFF_INVS);
  double* spart = (double*)(ws + OFF_SPART);
  float*  gT    = (float*)(ws + OFF_GT);

  hipLaunchKernelGGL(k_enc_partial, dim3(512), dim3(256), 0, stream, x, enc_w, part);
  hipLaunchKernelGGL(k_head, dim3(1), dim3(512), 0, stream, part, enc_b, bw_w, bw_b, enc_d, invw2);
  hipLaunchKernelGGL(k_gt, dim3(3125), dim3(256), 0, stream, decoder, enc_d, gT);
  hipLaunchKernelGGL(k_spart, dim3(SBLK), dim3(1024), 0, stream, nd, labels, invw2, spart);
  hipLaunchKernelGGL(k_sreduce, dim3(4), dim3(256), 0, stream, spart, invS);
  hipLaunchKernelGGL(k_main, dim3(1600), dim3(256), 0, stream, nd, nid, labels, gT, invw2, invS, out, 6400);
}

// Round 2
// 205.982 us; speedup vs baseline: 1.0487x; 1.0487x over previous
//
#include <hip/hip_runtime.h>

// Problem constants
#define NPTS 100000
#define NCH 32      // n
#define KNB 32      // K
#define MCL 16      // M

constexpr int IB1  = 128;   // i-blocks in encoder partial kernel
constexpr int SBLK = 250;   // blocks in S-partial kernel
constexpr int STILE = 64;   // points per LDS tile in S kernel

// Workspace layout (bytes) — all offsets 16B-aligned
constexpr size_t OFF_ENC_PART = 0;                          // 32*128 doubles = 32768
constexpr size_t OFF_ENC      = 32768;                      // 32 doubles     = 256
constexpr size_t OFF_INVW2    = OFF_ENC + 256;              // 512 floats     = 2048
constexpr size_t OFF_INVS     = OFF_INVW2 + 2048;           // 1024 floats    = 4096
constexpr size_t OFF_SPART    = OFF_INVS + 4096;            // 250*1024 dbl   = 2048000
constexpr size_t OFF_GT       = OFF_SPART + 2048000;        // N*32 floats    = 12800000

// ---------------------------------------------------------------------------
// Kernel 1: encoder matvec partials. encoded[j] = sum_i enc_w[j,i]*x[i]
__global__ __launch_bounds__(256) void k_enc_partial(
    const float* __restrict__ x, const float* __restrict__ enc_w,
    double* __restrict__ part) {
  int jg = blockIdx.x & 3;
  int ib = blockIdx.x >> 2;
  int j0 = jg * 8;
  int tid = threadIdx.x;
  double acc[8];
#pragma unroll
  for (int jj = 0; jj < 8; ++jj) acc[jj] = 0.0;
  for (int i = ib * 256 + tid; i < NPTS; i += IB1 * 256) {
    float xv = x[i];
#pragma unroll
    for (int jj = 0; jj < 8; ++jj)
      acc[jj] += (double)enc_w[(size_t)(j0 + jj) * NPTS + i] * (double)xv;
  }
#pragma unroll
  for (int jj = 0; jj < 8; ++jj) {
    double v = acc[jj];
#pragma unroll
    for (int off = 32; off >= 1; off >>= 1) v += __shfl_down(v, off);
    acc[jj] = v;
  }
  __shared__ double sw[4][8];
  int lane = tid & 63, w = tid >> 6;
  if (lane == 0)
    for (int jj = 0; jj < 8; ++jj) sw[w][jj] = acc[jj];
  __syncthreads();
  if (tid < 8) {
    double s = sw[0][tid] + sw[1][tid] + sw[2][tid] + sw[3][tid];
    part[(size_t)(j0 + tid) * IB1 + ib] = s;
  }
}

// ---------------------------------------------------------------------------
// Kernel 2: reduce encoder partials; bandwidths = bw_w@encoded + bw_b;
// invw2[m*32+j] = 1/w^2  (MU=1). One block, 512 threads (one per bw row).
__global__ __launch_bounds__(512) void k_head(
    const double* __restrict__ part, const float* __restrict__ enc_b,
    const float* __restrict__ bw_w, const float* __restrict__ bw_b,
    double* __restrict__ enc_out, float* __restrict__ invw2) {
  __shared__ double es[32];
  int tid = threadIdx.x;
  if (tid < 32) {
    double s = 0.0;
    for (int ib = 0; ib < IB1; ++ib) s += part[(size_t)tid * IB1 + ib];
    s += (double)enc_b[tid];
    enc_out[tid] = s;
    es[tid] = s;
  }
  __syncthreads();
  int r = tid;  // bw row = j*16 + m
  double wd = 0.0;
  for (int c = 0; c < 32; ++c) wd += (double)bw_w[r * 32 + c] * es[c];
  wd += (double)bw_b[r];
  int j = r >> 4, m = r & 15;
  invw2[m * 32 + j] = (float)(1.0 / (wd * wd));
}

// ---------------------------------------------------------------------------
// Kernel 3: gT[i*32+j] = (float)enc[j] * decoder[j*N+i]
__global__ __launch_bounds__(256) void k_gt(
    const float* __restrict__ decoder, const double* __restrict__ enc,
    float* __restrict__ gT) {
  __shared__ float tile[32][33];
  __shared__ float ef[32];
  int tx = threadIdx.x & 31, ty = threadIdx.x >> 5;  // ty: 0..7
  if (threadIdx.x < 32) ef[threadIdx.x] = (float)enc[threadIdx.x];
  int i0 = blockIdx.x * 32;
  for (int jj = ty; jj < 32; jj += 8)
    tile[tx][jj] = decoder[(size_t)jj * NPTS + i0 + tx];
  __syncthreads();
  for (int ii = ty; ii < 32; ii += 8)
    gT[(size_t)(i0 + ii) * 32 + tx] = tile[ii][tx] * ef[tx];
}

// ---------------------------------------------------------------------------
// Kernel 4: S[j,k] partials.
__global__ __launch_bounds__(1024) void k_spart(
    const float* __restrict__ nd, const int* __restrict__ labels,
    const float* __restrict__ invw2, double* __restrict__ spart) {
  __shared__ float iw[512];
  __shared__ float d2t[STILE * 32];
  __shared__ float ic[STILE * 32];
  int tid = threadIdx.x;
  if (tid < 512) iw[tid] = invw2[tid];
  int j = tid >> 5, k = tid & 31;
  double acc = 0.0;
  const int ntiles = (NPTS + STILE - 1) / STILE;  // 1563
  for (int tile = blockIdx.x; tile < ntiles; tile += SBLK) {
    int i0 = tile * STILE;
    __syncthreads();
#pragma unroll
    for (int q = tid; q < STILE * 32; q += 1024) {
      int ii = q >> 5;
      int gi = i0 + ii;
      float v = (gi < NPTS) ? nd[(size_t)i0 * 32 + q] : 1.0e18f;
      d2t[q] = v * v;
      int lab = (gi < NPTS) ? labels[gi] : 0;
      ic[q] = iw[lab * 32 + (q & 31)];
    }
    __syncthreads();
    float ts = 0.0f;
#pragma unroll 8
    for (int ii = 0; ii < STILE; ++ii)
      ts += fmaxf(fmaf(-d2t[ii * 32 + k], ic[ii * 32 + j], 1.0f), 0.0f);
    acc += (double)ts;
  }
  spart[(size_t)blockIdx.x * 1024 + tid] = acc;
}

// ---------------------------------------------------------------------------
// Kernel 5: reduce S partials -> invS[k*32+j] (f32). 4 blocks x 256.
__global__ __launch_bounds__(256) void k_sreduce(
    const double* __restrict__ spart, float* __restrict__ invS) {
  int t = blockIdx.x * 256 + threadIdx.x;  // 0..1023 = j*32+k
  double s = 0.0;
  for (int b = 0; b < SBLK; ++b) s += spart[(size_t)b * 1024 + t];
  int j = t >> 5, k = t & 31;
  invS[k * 32 + j] = (float)(1.0 / s);
}

// ---------------------------------------------------------------------------
// Kernel 6 v2: one wave per point-pair. lane l: quad q=l&7 covers j=q*4..q*4+3,
// k-group g=l>>3; pass kk gives k=kk*8+g. Gather is 8 lanes x dwordx4 = 128B
// per (point,k) column. Two points interleaved per iteration for MLP
// (8 independent dwordx4 gathers in flight vs 1 scalar load before).
__device__ __forceinline__ double point_partial(
    int i, const float* __restrict__ nd, const int* __restrict__ nid,
    const int* __restrict__ labels, const float* __restrict__ gT,
    const float* iw, const float* is, int lane) {
  int q = lane & 7;
  int g = lane >> 3;
  int lab = labels[i];
  int base = i * 32;
  int myid = nid[base + (lane & 31)];
  float myd = nd[base + (lane & 31)];
  float4 iwv = *(const float4*)&iw[lab * 32 + q * 4];
  double acc = 0.0;
#pragma unroll
  for (int kk = 0; kk < 4; ++kk) {
    int k = kk * 8 + g;
    int id = __shfl(myid, k);
    float dv = __shfl(myd, k);
    float4 gv = *(const float4*)&gT[(size_t)id * 32 + q * 4];
    float4 sv = *(const float4*)&is[k * 32 + q * 4];
    float md2 = -dv * dv;
    float t0 = fmaxf(fmaf(md2, iwv.x, 1.0f), 0.0f);
    float t1 = fmaxf(fmaf(md2, iwv.y, 1.0f), 0.0f);
    float t2 = fmaxf(fmaf(md2, iwv.z, 1.0f), 0.0f);
    float t3 = fmaxf(fmaf(md2, iwv.w, 1.0f), 0.0f);
    acc += (double)(gv.x * (t0 * sv.x));
    acc += (double)(gv.y * (t1 * sv.y));
    acc += (double)(gv.z * (t2 * sv.z));
    acc += (double)(gv.w * (t3 * sv.w));
  }
  return acc;
}

__global__ __launch_bounds__(256) void k_main(
    const float* __restrict__ nd, const int* __restrict__ nid,
    const int* __restrict__ labels, const float* __restrict__ gT,
    const float* __restrict__ invw2, const float* __restrict__ invS,
    float* __restrict__ out, int nwaves) {
  __shared__ __align__(16) float iw[512];
  __shared__ __align__(16) float is[1024];
  int tid = threadIdx.x;
  for (int qq = tid; qq < 512; qq += 256) iw[qq] = invw2[qq];
  for (int qq = tid; qq < 1024; qq += 256) is[qq] = invS[qq];
  __syncthreads();
  int lane = tid & 63;
  int w = tid >> 6;
  int wid = blockIdx.x * 4 + w;
  // nwaves=5000: base strides of 10000 cover all points as {base, base+5000};
  // 10 iterations exactly, no tail.
  for (int base = wid; base < NPTS; base += 2 * nwaves) {
    int i0 = base;
    int i1 = base + nwaves;
    double a0 = point_partial(i0, nd, nid, labels, gT, iw, is, lane);
    double a1 = point_partial(i1, nd, nid, labels, gT, iw, is, lane);
#pragma unroll
    for (int off = 32; off >= 1; off >>= 1) {
      a0 += __shfl_down(a0, off);
      a1 += __shfl_down(a1, off);
    }
    if (lane == 0) {
      out[i0] = (float)a0;
      out[i1] = (float)a1;
    }
  }
}

// ---------------------------------------------------------------------------
extern "C" void kernel_launch(void* const* d_in, const int* in_sizes, int n_in,
                              void* d_out, int out_size, void* d_ws,
                              size_t ws_size, hipStream_t stream) {
  const float* x       = (const float*)d_in[0];
  const float* enc_w   = (const float*)d_in[1];
  const float* enc_b   = (const float*)d_in[2];
  const float* decoder = (const float*)d_in[3];
  const float* bw_w    = (const float*)d_in[4];
  const float* bw_b    = (const float*)d_in[5];
  const float* nd      = (const float*)d_in[6];
  const int*   nid     = (const int*)d_in[7];
  const int*   labels  = (const int*)d_in[8];
  float* out = (float*)d_out;

  char* ws = (char*)d_ws;
  double* part  = (double*)(ws + OFF_ENC_PART);
  double* enc_d = (double*)(ws + OFF_ENC);
  float*  invw2 = (float*)(ws + OFF_INVW2);
  float*  invS  = (float*)(ws + OFF_INVS);
  double* spart = (double*)(ws + OFF_SPART);
  float*  gT    = (float*)(ws + OFF_GT);

  hipLaunchKernelGGL(k_enc_partial, dim3(512), dim3(256), 0, stream, x, enc_w, part);
  hipLaunchKernelGGL(k_head, dim3(1), dim3(512), 0, stream, part, enc_b, bw_w, bw_b, enc_d, invw2);
  hipLaunchKernelGGL(k_gt, dim3(3125), dim3(256), 0, stream, decoder, enc_d, gT);
  hipLaunchKernelGGL(k_spart, dim3(SBLK), dim3(1024), 0, stream, nd, labels, invw2, spart);
  hipLaunchKernelGGL(k_sreduce, dim3(4), dim3(256), 0, stream, spart, invS);
  // 1250 blocks x 4 waves = 5000 waves; 2 points/wave/iter x 10 iters = 100000
  hipLaunchKernelGGL(k_main, dim3(1250), dim3(256), 0, stream, nd, nid, labels, gT, invw2, invS, out, 5000);
}